// Round 7
// baseline (367.714 us; speedup 1.0000x reference)
//
#include <hip/hip_runtime.h>
#include <float.h>

// LocalAttention: B=4, N=4096, DIM=1024, WINDOW=128. v2=k2 reference bug
// exploited (V projection dead). bf16 MFMA 16x16x32, fp32 acc.
// R7: drop ktr (k_pv transposes k2 in LDS from kbuf); fuse sim+softmax into
// k_simsm (register sim + shfl/LDS row softmax); qk/out keep 8-phase core.

#define B_SZ 4
#define SEQ 4096
#define DIM 1024
#define WIN 128
#define NWIN 32
#define TW 256
#define NROWS (B_SZ * SEQ)     // 16384
#define KPAD 4224              // 128 zero rows + 4096 tokens per batch

typedef float f32x4 __attribute__((ext_vector_type(4)));
typedef __bf16 bf16x8 __attribute__((ext_vector_type(8)));
typedef unsigned short u16x8 __attribute__((ext_vector_type(8)));

__device__ __forceinline__ unsigned short f2b(float f) {
    unsigned int u = __float_as_uint(f);
    u += 0x7FFF + ((u >> 16) & 1);          // round-to-nearest-even
    return (unsigned short)(u >> 16);
}

__device__ __forceinline__ void gld_lds16(const unsigned short* g, unsigned short* l) {
    __builtin_amdgcn_global_load_lds(
        (const __attribute__((address_space(1))) void*)g,
        (__attribute__((address_space(3))) void*)l, 16, 0, 0);
}

// ===========================================================================
// 256x256 8-phase GEMM core (R5 schedule, best measured for the dense GEMMs).
// ===========================================================================
__device__ __forceinline__ bf16x8 lds_read_swz(const unsigned short* tb, int row, int kbyte) {
    int L = row * 128 + kbyte;
    L ^= ((L >> 9) & 1) << 5;
    return *(const bf16x8*)((const char*)tb + L);
}

#define BAR __builtin_amdgcn_s_barrier()
#define PRI1 __builtin_amdgcn_s_setprio(1)
#define PRI0 __builtin_amdgcn_s_setprio(0)
#define LGKM0 do { asm volatile("s_waitcnt lgkmcnt(0)" ::: "memory"); \
                   __builtin_amdgcn_sched_barrier(0); } while (0)
#define VMW(N) do { asm volatile("s_waitcnt vmcnt(" #N ")" ::: "memory"); \
                    __builtin_amdgcn_sched_barrier(0); } while (0)

#define LDAF(BUF, MH)                                                        \
    _Pragma("unroll") for (int m_ = 0; m_ < 4; ++m_)                         \
    _Pragma("unroll") for (int ks_ = 0; ks_ < 2; ++ks_)                      \
        afq[MH][m_][ks_] = lds_read_swz(bufA[BUF],                           \
            wr * 128 + (MH) * 64 + m_ * 16 + fr, ks_ * 64 + kby);

#define LDBF(BUF, NH)                                                        \
    _Pragma("unroll") for (int n_ = 0; n_ < 2; ++n_)                         \
    _Pragma("unroll") for (int ks_ = 0; ks_ < 2; ++ks_)                      \
        bfq[n_][ks_] = lds_read_swz(bufB[BUF],                               \
            wc * 64 + (NH) * 32 + n_ * 16 + fr, ks_ * 64 + kby);

#define MFQ(MH, NH)                                                          \
    _Pragma("unroll") for (int ks_ = 0; ks_ < 2; ++ks_)                      \
    _Pragma("unroll") for (int m_ = 0; m_ < 4; ++m_)                         \
    _Pragma("unroll") for (int n_ = 0; n_ < 2; ++n_)                         \
        acc[(MH) * 4 + m_][(NH) * 2 + n_] =                                  \
            __builtin_amdgcn_mfma_f32_16x16x32_bf16(afq[MH][m_][ks_],        \
                bfq[n_][ks_], acc[(MH) * 4 + m_][(NH) * 2 + n_], 0, 0, 0);

#define STG_HA(BUF, HALF, K0)                                                \
    { gld_lds16(A + soffA[(HALF) * 2 + 0] + (K0), bufA[BUF] + ldst[(HALF) * 2 + 0]); \
      gld_lds16(A + soffA[(HALF) * 2 + 1] + (K0), bufA[BUF] + ldst[(HALF) * 2 + 1]); }
#define STG_HB(BUF, HALF, K0)                                                \
    { gld_lds16(Bt + soffB[(HALF) * 2 + 0] + (K0), bufB[BUF] + ldst[(HALF) * 2 + 0]); \
      gld_lds16(Bt + soffB[(HALF) * 2 + 1] + (K0), bufB[BUF] + ldst[(HALF) * 2 + 1]); }

__device__ __forceinline__ void core256(
    const unsigned short* __restrict__ A, int lda,
    const unsigned short* __restrict__ Bt, int ldb, int K,
    unsigned short* lds, f32x4 (&acc)[8][4],
    int wid, int lane, int wr, int wc)
{
    unsigned short* bufA[2] = { lds, lds + 32768 };
    unsigned short* bufB[2] = { lds + 16384, lds + 49152 };

    const int kby = (lane >> 4) * 16;
    const int fr = lane & 15;

    int soffA[4], soffB[4], ldst[4];
#pragma unroll
    for (int hj = 0; hj < 4; ++hj) {
        const int half = hj >> 1, j = hj & 1;
        const int P = half * 16384 + wid * 2048 + j * 1024 + lane * 16;
        const int L = P ^ (((P >> 9) & 1) << 5);
        const int row = L >> 7, col = (L & 127) >> 1;
        soffA[hj] = row * lda + col;
        soffB[hj] = row * ldb + col;
        ldst[hj] = (half * 16384 + wid * 2048 + j * 1024) >> 1;
    }

    bf16x8 afq[2][4][2], bfq[2][2];
#pragma unroll
    for (int m = 0; m < 8; ++m)
#pragma unroll
        for (int n = 0; n < 4; ++n) acc[m][n] = (f32x4){0.f, 0.f, 0.f, 0.f};

    STG_HA(0, 0, 0); STG_HA(0, 1, 0); STG_HB(0, 0, 0); STG_HB(0, 1, 0);
    STG_HA(1, 0, 64); STG_HA(1, 1, 64); STG_HB(1, 0, 64);
    VMW(6);
    BAR;

    const int NITER = K >> 7;
#pragma unroll 1
    for (int i = 0; i < NITER; ++i) {
        const bool st = (i + 1 < NITER);
        const int ku1 = (2 * i + 1) * 64;
        const int ku2 = (2 * i + 2) * 64;
        const int ku3 = (2 * i + 3) * 64;

        LDAF(0, 0); LDBF(0, 0);
        STG_HB(1, 1, ku1);
        BAR; LGKM0; PRI1; MFQ(0, 0); PRI0; BAR;
        LDAF(0, 1);
        BAR; LGKM0; PRI1; MFQ(1, 0); PRI0; BAR;
        LDBF(0, 1);
        if (st) STG_HA(0, 0, ku2);
        BAR; LGKM0; PRI1; MFQ(1, 1); PRI0; BAR;
        if (st) { STG_HA(0, 1, ku2); VMW(4); } else { VMW(0); }
        BAR; PRI1; MFQ(0, 1); PRI0; BAR;
        LDAF(1, 0); LDBF(1, 0);
        if (st) STG_HB(0, 0, ku2);
        BAR; LGKM0; PRI1; MFQ(0, 0); PRI0; BAR;
        LDAF(1, 1);
        if (st) STG_HB(0, 1, ku2);
        BAR; LGKM0; PRI1; MFQ(1, 0); PRI0; BAR;
        LDBF(1, 1);
        if (st) STG_HA(1, 0, ku3);
        BAR; LGKM0; PRI1; MFQ(1, 1); PRI0; BAR;
        if (st) { STG_HA(1, 1, ku3); STG_HB(1, 0, ku3); VMW(6); } else { VMW(0); }
        BAR; PRI1; MFQ(0, 1); PRI0; BAR;
    }
}

// ---------------------------------------------------------------------------
// Prepass kernels
// ---------------------------------------------------------------------------
__global__ __launch_bounds__(256) void k_prep_x(const float* __restrict__ x,
                                                unsigned short* __restrict__ xb)
{
    int i = blockIdx.x * 256 + threadIdx.x;
    float4 a = *(const float4*)&x[(size_t)i * 8];
    float4 b = *(const float4*)&x[(size_t)i * 8 + 4];
    ushort4 lo, hi;
    lo.x = f2b(a.x); lo.y = f2b(a.y); lo.z = f2b(a.z); lo.w = f2b(a.w);
    hi.x = f2b(b.x); hi.y = f2b(b.y); hi.z = f2b(b.z); hi.w = f2b(b.w);
    *(ushort4*)&xb[(size_t)i * 8] = lo;
    *(ushort4*)&xb[(size_t)i * 8 + 4] = hi;
}

__global__ __launch_bounds__(256) void k_transpose(const float* __restrict__ src,
    int src_ld, int col0, int R, unsigned short* __restrict__ dst)
{
    __shared__ float T[32][33];
    const int r0 = blockIdx.y * 32, c0 = blockIdx.x * 32;
    const int cx = threadIdx.x & 31, ry = threadIdx.x >> 5;
#pragma unroll
    for (int i = 0; i < 4; ++i)
        T[ry + 8 * i][cx] = src[(size_t)(r0 + ry + 8 * i) * src_ld + col0 + c0 + cx];
    __syncthreads();
#pragma unroll
    for (int i = 0; i < 4; ++i)
        dst[(size_t)(c0 + ry + 8 * i) * R + r0 + cx] = f2b(T[cx][ry + 8 * i]);
}

__global__ __launch_bounds__(256) void k_zero_kpad(unsigned short* __restrict__ kbuf)
{
    int t = blockIdx.x * 256 + threadIdx.x;
    int b = t >> 14, r = t & 16383;
    float4 z = {0.f, 0.f, 0.f, 0.f};
    *(float4*)&kbuf[(size_t)b * KPAD * DIM + (size_t)r * 8] = z;
}

// ---------------------------------------------------------------------------
// qk-proj (256^2 8-phase): q -> qbuf, k -> kbuf only (ktr dropped).
// ---------------------------------------------------------------------------
__global__ __launch_bounds__(512, 2) void k_gemm_qk(
    const unsigned short* __restrict__ xb, const unsigned short* __restrict__ wqkvT,
    unsigned short* __restrict__ qbuf, unsigned short* __restrict__ kbuf)
{
    __shared__ unsigned short lds[65536];
    const int tid = threadIdx.x, wid = tid >> 6, lane = tid & 63;
    const int wr = wid >> 2, wc = wid & 3;
    const int wg = blockIdx.x;
    const int x = (wg & 7) * 64 + (wg >> 3);
    const int bm = (x & 63) * 256;
    const int bn = (x >> 6) * 256;

    f32x4 acc[8][4];
    core256(xb + (size_t)bm * DIM, DIM, wqkvT + (size_t)bn * DIM, DIM, DIM,
            lds, acc, wid, lane, wr, wc);

    const int fr = lane & 15;
#pragma unroll
    for (int m = 0; m < 8; ++m) {
        const int row0 = bm + wr * 128 + m * 16 + (lane >> 4) * 4;
#pragma unroll
        for (int n = 0; n < 4; ++n) {
            const int col = bn + wc * 64 + n * 16 + fr;
            if (col < DIM) {
#pragma unroll
                for (int r = 0; r < 4; ++r)
                    qbuf[(size_t)(row0 + r) * DIM + col] = f2b(acc[m][n][r]);
            } else {
                const int d = col - DIM;
                const int b = row0 >> 12, tok0 = row0 & 4095;
#pragma unroll
                for (int r = 0; r < 4; ++r)
                    kbuf[((size_t)b * KPAD + 128 + tok0 + r) * DIM + d] = f2b(acc[m][n][r]);
            }
        }
    }
}

// ---------------------------------------------------------------------------
// out-proj (256^2 8-phase) + bias -> fp32 d_out.
// ---------------------------------------------------------------------------
__global__ __launch_bounds__(512, 2) void k_out(
    const unsigned short* __restrict__ aout, const unsigned short* __restrict__ woutT,
    const float* __restrict__ bias, float* __restrict__ out)
{
    __shared__ unsigned short lds[65536];
    const int tid = threadIdx.x, wid = tid >> 6, lane = tid & 63;
    const int wr = wid >> 2, wc = wid & 3;
    const int wg = blockIdx.x;
    const int x = (wg & 7) * 32 + (wg >> 3);
    const int bm = (x & 63) * 256;
    const int bn = (x >> 6) * 256;

    f32x4 acc[8][4];
    core256(aout + (size_t)bm * DIM, DIM, woutT + (size_t)bn * DIM, DIM, DIM,
            lds, acc, wid, lane, wr, wc);

    const int fr = lane & 15;
#pragma unroll
    for (int m = 0; m < 8; ++m) {
        const int row0 = bm + wr * 128 + m * 16 + (lane >> 4) * 4;
#pragma unroll
        for (int n = 0; n < 4; ++n) {
            const int col = bn + wc * 64 + n * 16 + fr;
            const float bb = bias[col];
#pragma unroll
            for (int r = 0; r < 4; ++r)
                out[(size_t)(row0 + r) * DIM + col] = acc[m][n][r] + bb;
        }
    }
}

// ---------------------------------------------------------------------------
// Fused sim+softmax: block = (mh, win). 512 thr = 8 waves (2M x 4N) over a
// 64x256 score tile; K=1024 staged loop; row softmax via shfl_xor over the
// 16 col-lanes + LDS cross-wave stats; writes bf16 P to attnb.
// ---------------------------------------------------------------------------
__global__ __launch_bounds__(512) void k_simsm(
    const unsigned short* __restrict__ qbuf, const unsigned short* __restrict__ kbuf,
    unsigned short* __restrict__ attnb)
{
    __shared__ unsigned short As[64 * 64];    // 8 KB
    __shared__ unsigned short Bs[256 * 64];   // 32 KB
    __shared__ float smax[4][64];
    __shared__ float ssum[4][64];

    const int mh = blockIdx.x, win = blockIdx.y;
    const int b = win >> 5, w = win & 31;
    const int tid = threadIdx.x, wid = tid >> 6, lane = tid & 63;
    const int wr = wid >> 2, wc = wid & 3;
    const int hi = lane >> 4, fr = lane & 15;

    const unsigned short* A  = qbuf + (size_t)(b * SEQ + w * WIN + mh * 64) * DIM;
    const unsigned short* Bt = kbuf + ((size_t)b * KPAD + w * WIN) * DIM;

    f32x4 acc[2][4];
#pragma unroll
    for (int m = 0; m < 2; ++m)
#pragma unroll
        for (int n = 0; n < 4; ++n) acc[m][n] = (f32x4){0.f, 0.f, 0.f, 0.f};

    for (int k0 = 0; k0 < DIM; k0 += 64) {
        gld_lds16(A + (size_t)(wid * 8 + (lane >> 3)) * DIM + k0 + (lane & 7) * 8,
                  As + wid * 512);
#pragma unroll
        for (int it = 0; it < 4; ++it)
            gld_lds16(Bt + (size_t)(it * 64 + wid * 8 + (lane >> 3)) * DIM + k0 + (lane & 7) * 8,
                      Bs + it * 4096 + wid * 512);
        __syncthreads();
#pragma unroll
        for (int ks = 0; ks < 2; ++ks) {
            bf16x8 af[2], bf[4];
            const int kof = ks * 32 + hi * 8;
#pragma unroll
            for (int m = 0; m < 2; ++m)
                af[m] = *(const bf16x8*)(As + (wr * 32 + m * 16 + fr) * 64 + kof);
#pragma unroll
            for (int n = 0; n < 4; ++n)
                bf[n] = *(const bf16x8*)(Bs + (wc * 64 + n * 16 + fr) * 64 + kof);
#pragma unroll
            for (int m = 0; m < 2; ++m)
#pragma unroll
                for (int n = 0; n < 4; ++n)
                    acc[m][n] = __builtin_amdgcn_mfma_f32_16x16x32_bf16(
                        af[m], bf[n], acc[m][n], 0, 0, 0);
        }
        __syncthreads();
    }

    // scale + causal mask, in registers
    const float scale = 0.03125f;
    float ms[2][4][4];
#pragma unroll
    for (int m = 0; m < 2; ++m)
#pragma unroll
        for (int r = 0; r < 4; ++r) {
            const int qi = mh * 64 + wr * 32 + m * 16 + hi * 4 + r;
#pragma unroll
            for (int n = 0; n < 4; ++n) {
                const int jc = wc * 64 + n * 16 + fr;
                ms[m][n][r] = (jc > qi + WIN) ? -FLT_MAX : acc[m][n][r] * scale;
            }
        }

    // row max: lane-local over n, shfl over the 16 col-lanes, LDS across waves
    float pmv[2][4];
#pragma unroll
    for (int m = 0; m < 2; ++m)
#pragma unroll
        for (int r = 0; r < 4; ++r) {
            float pm = fmaxf(fmaxf(ms[m][0][r], ms[m][1][r]),
                             fmaxf(ms[m][2][r], ms[m][3][r]));
#pragma unroll
            for (int off = 1; off < 16; off <<= 1) pm = fmaxf(pm, __shfl_xor(pm, off));
            pmv[m][r] = pm;
        }
    if (fr == 0) {
#pragma unroll
        for (int m = 0; m < 2; ++m)
#pragma unroll
            for (int r = 0; r < 4; ++r)
                smax[wc][wr * 32 + m * 16 + hi * 4 + r] = pmv[m][r];
    }
    __syncthreads();

    float e[2][4][4], psv[2][4];
#pragma unroll
    for (int m = 0; m < 2; ++m)
#pragma unroll
        for (int r = 0; r < 4; ++r) {
            const int rl = wr * 32 + m * 16 + hi * 4 + r;
            const float rm = fmaxf(fmaxf(smax[0][rl], smax[1][rl]),
                                   fmaxf(smax[2][rl], smax[3][rl]));
            float s = 0.f;
#pragma unroll
            for (int n = 0; n < 4; ++n) {
                e[m][n][r] = expf(ms[m][n][r] - rm);
                s += e[m][n][r];
            }
#pragma unroll
            for (int off = 1; off < 16; off <<= 1) s += __shfl_xor(s, off);
            psv[m][r] = s;
        }
    if (fr == 0) {
#pragma unroll
        for (int m = 0; m < 2; ++m)
#pragma unroll
            for (int r = 0; r < 4; ++r)
                ssum[wc][wr * 32 + m * 16 + hi * 4 + r] = psv[m][r];
    }
    __syncthreads();

#pragma unroll
    for (int m = 0; m < 2; ++m)
#pragma unroll
        for (int r = 0; r < 4; ++r) {
            const int rl = wr * 32 + m * 16 + hi * 4 + r;
            const float inv = 1.f / (ssum[0][rl] + ssum[1][rl] + ssum[2][rl] + ssum[3][rl]);
            const size_t rowg = (size_t)win * WIN + mh * 64 + rl;
#pragma unroll
            for (int n = 0; n < 4; ++n)
                attnb[rowg * TW + wc * 64 + n * 16 + fr] = f2b(e[m][n][r] * inv);
        }
}

// ---------------------------------------------------------------------------
// PV: out = P @ k2 (v2 = k2). Per block (ct, win): 128 rows x 128 d cols,
// K = 256 toks. B-tile transposed in LDS from kbuf (coalesced global reads,
// scalar ds_writes). 256 thr = 4 waves (2x2).
// ---------------------------------------------------------------------------
__global__ __launch_bounds__(256) void k_pv(
    const unsigned short* __restrict__ attnb, const unsigned short* __restrict__ kbuf,
    unsigned short* __restrict__ aout)
{
    __shared__ unsigned short As[128 * 64];   // P tile 128 x 64tok
    __shared__ unsigned short Bs[128 * 64];   // k2^T tile: [d 128][tok 64]

    const int win = blockIdx.y, ct = blockIdx.x;
    const int b = win >> 5, w = win & 31;
    const int tid = threadIdx.x, wv = tid >> 6, lane = tid & 63;
    const int wr = wv >> 1, wc = wv & 1;

    const unsigned short* Ap = attnb + (size_t)win * WIN * TW;
    const unsigned short* Kp = kbuf + ((size_t)b * KPAD + w * WIN) * DIM + ct * 128;

    f32x4 acc[4][4];
#pragma unroll
    for (int m = 0; m < 4; ++m)
#pragma unroll
        for (int n = 0; n < 4; ++n) acc[m][n] = (f32x4){0.f, 0.f, 0.f, 0.f};

    for (int k0 = 0; k0 < TW; k0 += 64) {
        // coalesced source reads: 16 lanes cover one tok row's 128 d elems
        u16x8 v[4];
#pragma unroll
        for (int it = 0; it < 4; ++it)
            v[it] = *(const u16x8*)&Kp[(size_t)(k0 + it * 16 + (tid >> 4)) * DIM + (tid & 15) * 8];
        __syncthreads();   // previous iteration's LDS reads complete
        // transposed LDS writes: Bs[d][tok]
#pragma unroll
        for (int it = 0; it < 4; ++it) {
            const int tok = it * 16 + (tid >> 4);
            const int d0 = (tid & 15) * 8;
#pragma unroll
            for (int ee = 0; ee < 8; ++ee)
                Bs[(d0 + ee) * 64 + tok] = v[it][ee];
        }
        // P tile staging (linear, global_load_lds)
#pragma unroll
        for (int it = 0; it < 4; ++it)
            gld_lds16(Ap + (size_t)(wv * 32 + it * 8 + (lane >> 3)) * TW + k0 + (lane & 7) * 8,
                      As + (wv * 32 + it * 8) * 64);
        __syncthreads();

#pragma unroll
        for (int ks = 0; ks < 2; ++ks) {
            bf16x8 af[4], bfr[4];
            const int kof = ks * 32 + (lane >> 4) * 8;
#pragma unroll
            for (int m = 0; m < 4; ++m)
                af[m] = *(const bf16x8*)(As + (wr * 64 + m * 16 + (lane & 15)) * 64 + kof);
#pragma unroll
            for (int n = 0; n < 4; ++n)
                bfr[n] = *(const bf16x8*)(Bs + (wc * 64 + n * 16 + (lane & 15)) * 64 + kof);
#pragma unroll
            for (int m = 0; m < 4; ++m)
#pragma unroll
                for (int n = 0; n < 4; ++n)
                    acc[m][n] = __builtin_amdgcn_mfma_f32_16x16x32_bf16(
                        af[m], bfr[n], acc[m][n], 0, 0, 0);
        }
        __syncthreads();
    }

#pragma unroll
    for (int m = 0; m < 4; ++m) {
        const int row0 = wr * 64 + m * 16 + (lane >> 4) * 4;
#pragma unroll
        for (int n = 0; n < 4; ++n) {
            const int col = ct * 128 + wc * 64 + n * 16 + (lane & 15);
#pragma unroll
            for (int r = 0; r < 4; ++r)
                aout[((size_t)b * SEQ + w * WIN + row0 + r) * DIM + col] =
                    f2b(acc[m][n][r]);
        }
    }
}

// ---------------------------------------------------------------------------
extern "C" void kernel_launch(void* const* d_in, const int* in_sizes, int n_in,
                              void* d_out, int out_size, void* d_ws, size_t ws_size,
                              hipStream_t stream)
{
    const float* x     = (const float*)d_in[0];
    const float* w_qkv = (const float*)d_in[1];
    const float* w_out = (const float*)d_in[2];
    const float* b_out = (const float*)d_in[3];
    float* out = (float*)d_out;

    char* p = (char*)d_ws;
    unsigned short* xb    = (unsigned short*)p; p += (size_t)NROWS * DIM * 2;
    unsigned short* wqkvT = (unsigned short*)p; p += (size_t)2 * DIM * DIM * 2;
    unsigned short* woutT = (unsigned short*)p; p += (size_t)DIM * DIM * 2;
    unsigned short* qbuf  = (unsigned short*)p; p += (size_t)NROWS * DIM * 2;
    unsigned short* kbuf  = (unsigned short*)p; p += (size_t)B_SZ * KPAD * DIM * 2;
    unsigned short* attnb = (unsigned short*)p; p += (size_t)NROWS * TW * 2;
    unsigned short* aout  = (unsigned short*)p; p += (size_t)NROWS * DIM * 2;

    k_prep_x<<<NROWS * DIM / 8 / 256, 256, 0, stream>>>(x, xb);
    k_transpose<<<dim3(2 * DIM / 32, DIM / 32), 256, 0, stream>>>(w_qkv, 3 * DIM, 0, DIM, wqkvT);
    k_transpose<<<dim3(DIM / 32, DIM / 32), 256, 0, stream>>>(w_out, DIM, 0, DIM, woutT);
    k_zero_kpad<<<256, 256, 0, stream>>>(kbuf);

    k_gemm_qk<<<512, 512, 0, stream>>>(xb, wqkvT, qbuf, kbuf);
    k_simsm<<<dim3(2, B_SZ * NWIN), 512, 0, stream>>>(qbuf, kbuf, attnb);
    k_pv<<<dim3(DIM / 128, B_SZ * NWIN), 256, 0, stream>>>(attnb, kbuf, aout);
    k_out<<<256, 512, 0, stream>>>(aout, woutT, b_out, out);
}

// Round 8
// 347.950 us; speedup vs baseline: 1.0568x; 1.0568x over previous
//
#include <hip/hip_runtime.h>
#include <float.h>

// LocalAttention: B=4, N=4096, DIM=1024, WINDOW=128. v2=k2 reference bug
// exploited (V projection dead). bf16 MFMA 16x16x32, fp32 acc.
// R8: fully-fused attention kernel k_attn (QK^T + softmax + PV) with
// bank-conflict-free swizzled LDS everywhere. qk/out keep 8-phase core.

#define B_SZ 4
#define SEQ 4096
#define DIM 1024
#define WIN 128
#define NWIN 32
#define TW 256
#define NROWS (B_SZ * SEQ)     // 16384
#define KPAD 4224              // 128 zero rows + 4096 tokens per batch

typedef float f32x4 __attribute__((ext_vector_type(4)));
typedef __bf16 bf16x8 __attribute__((ext_vector_type(8)));
typedef unsigned short u16x8 __attribute__((ext_vector_type(8)));

__device__ __forceinline__ unsigned short f2b(float f) {
    unsigned int u = __float_as_uint(f);
    u += 0x7FFF + ((u >> 16) & 1);          // round-to-nearest-even
    return (unsigned short)(u >> 16);
}

__device__ __forceinline__ void gld_lds16(const unsigned short* g, unsigned short* l) {
    __builtin_amdgcn_global_load_lds(
        (const __attribute__((address_space(1))) void*)g,
        (__attribute__((address_space(3))) void*)l, 16, 0, 0);
}

// ===========================================================================
// 256x256 8-phase GEMM core (R5 schedule) — unchanged, for qk-proj/out-proj.
// ===========================================================================
__device__ __forceinline__ bf16x8 lds_read_swz(const unsigned short* tb, int row, int kbyte) {
    int L = row * 128 + kbyte;
    L ^= ((L >> 9) & 1) << 5;
    return *(const bf16x8*)((const char*)tb + L);
}

#define BAR __builtin_amdgcn_s_barrier()
#define PRI1 __builtin_amdgcn_s_setprio(1)
#define PRI0 __builtin_amdgcn_s_setprio(0)
#define LGKM0 do { asm volatile("s_waitcnt lgkmcnt(0)" ::: "memory"); \
                   __builtin_amdgcn_sched_barrier(0); } while (0)
#define VMW(N) do { asm volatile("s_waitcnt vmcnt(" #N ")" ::: "memory"); \
                    __builtin_amdgcn_sched_barrier(0); } while (0)

#define LDAF(BUF, MH)                                                        \
    _Pragma("unroll") for (int m_ = 0; m_ < 4; ++m_)                         \
    _Pragma("unroll") for (int ks_ = 0; ks_ < 2; ++ks_)                      \
        afq[MH][m_][ks_] = lds_read_swz(bufA[BUF],                           \
            wr * 128 + (MH) * 64 + m_ * 16 + fr, ks_ * 64 + kby);

#define LDBF(BUF, NH)                                                        \
    _Pragma("unroll") for (int n_ = 0; n_ < 2; ++n_)                         \
    _Pragma("unroll") for (int ks_ = 0; ks_ < 2; ++ks_)                      \
        bfq[n_][ks_] = lds_read_swz(bufB[BUF],                               \
            wc * 64 + (NH) * 32 + n_ * 16 + fr, ks_ * 64 + kby);

#define MFQ(MH, NH)                                                          \
    _Pragma("unroll") for (int ks_ = 0; ks_ < 2; ++ks_)                      \
    _Pragma("unroll") for (int m_ = 0; m_ < 4; ++m_)                         \
    _Pragma("unroll") for (int n_ = 0; n_ < 2; ++n_)                         \
        acc[(MH) * 4 + m_][(NH) * 2 + n_] =                                  \
            __builtin_amdgcn_mfma_f32_16x16x32_bf16(afq[MH][m_][ks_],        \
                bfq[n_][ks_], acc[(MH) * 4 + m_][(NH) * 2 + n_], 0, 0, 0);

#define STG_HA(BUF, HALF, K0)                                                \
    { gld_lds16(A + soffA[(HALF) * 2 + 0] + (K0), bufA[BUF] + ldst[(HALF) * 2 + 0]); \
      gld_lds16(A + soffA[(HALF) * 2 + 1] + (K0), bufA[BUF] + ldst[(HALF) * 2 + 1]); }
#define STG_HB(BUF, HALF, K0)                                                \
    { gld_lds16(Bt + soffB[(HALF) * 2 + 0] + (K0), bufB[BUF] + ldst[(HALF) * 2 + 0]); \
      gld_lds16(Bt + soffB[(HALF) * 2 + 1] + (K0), bufB[BUF] + ldst[(HALF) * 2 + 1]); }

__device__ __forceinline__ void core256(
    const unsigned short* __restrict__ A, int lda,
    const unsigned short* __restrict__ Bt, int ldb, int K,
    unsigned short* lds, f32x4 (&acc)[8][4],
    int wid, int lane, int wr, int wc)
{
    unsigned short* bufA[2] = { lds, lds + 32768 };
    unsigned short* bufB[2] = { lds + 16384, lds + 49152 };

    const int kby = (lane >> 4) * 16;
    const int fr = lane & 15;

    int soffA[4], soffB[4], ldst[4];
#pragma unroll
    for (int hj = 0; hj < 4; ++hj) {
        const int half = hj >> 1, j = hj & 1;
        const int P = half * 16384 + wid * 2048 + j * 1024 + lane * 16;
        const int L = P ^ (((P >> 9) & 1) << 5);
        const int row = L >> 7, col = (L & 127) >> 1;
        soffA[hj] = row * lda + col;
        soffB[hj] = row * ldb + col;
        ldst[hj] = (half * 16384 + wid * 2048 + j * 1024) >> 1;
    }

    bf16x8 afq[2][4][2], bfq[2][2];
#pragma unroll
    for (int m = 0; m < 8; ++m)
#pragma unroll
        for (int n = 0; n < 4; ++n) acc[m][n] = (f32x4){0.f, 0.f, 0.f, 0.f};

    STG_HA(0, 0, 0); STG_HA(0, 1, 0); STG_HB(0, 0, 0); STG_HB(0, 1, 0);
    STG_HA(1, 0, 64); STG_HA(1, 1, 64); STG_HB(1, 0, 64);
    VMW(6);
    BAR;

    const int NITER = K >> 7;
#pragma unroll 1
    for (int i = 0; i < NITER; ++i) {
        const bool st = (i + 1 < NITER);
        const int ku1 = (2 * i + 1) * 64;
        const int ku2 = (2 * i + 2) * 64;
        const int ku3 = (2 * i + 3) * 64;

        LDAF(0, 0); LDBF(0, 0);
        STG_HB(1, 1, ku1);
        BAR; LGKM0; PRI1; MFQ(0, 0); PRI0; BAR;
        LDAF(0, 1);
        BAR; LGKM0; PRI1; MFQ(1, 0); PRI0; BAR;
        LDBF(0, 1);
        if (st) STG_HA(0, 0, ku2);
        BAR; LGKM0; PRI1; MFQ(1, 1); PRI0; BAR;
        if (st) { STG_HA(0, 1, ku2); VMW(4); } else { VMW(0); }
        BAR; PRI1; MFQ(0, 1); PRI0; BAR;
        LDAF(1, 0); LDBF(1, 0);
        if (st) STG_HB(0, 0, ku2);
        BAR; LGKM0; PRI1; MFQ(0, 0); PRI0; BAR;
        LDAF(1, 1);
        if (st) STG_HB(0, 1, ku2);
        BAR; LGKM0; PRI1; MFQ(1, 0); PRI0; BAR;
        LDBF(1, 1);
        if (st) STG_HA(1, 0, ku3);
        BAR; LGKM0; PRI1; MFQ(1, 1); PRI0; BAR;
        if (st) { STG_HA(1, 1, ku3); STG_HB(1, 0, ku3); VMW(6); } else { VMW(0); }
        BAR; PRI1; MFQ(0, 1); PRI0; BAR;
    }
}

// ---------------------------------------------------------------------------
// Prepass kernels
// ---------------------------------------------------------------------------
__global__ __launch_bounds__(256) void k_prep_x(const float* __restrict__ x,
                                                unsigned short* __restrict__ xb)
{
    int i = blockIdx.x * 256 + threadIdx.x;
    float4 a = *(const float4*)&x[(size_t)i * 8];
    float4 b = *(const float4*)&x[(size_t)i * 8 + 4];
    ushort4 lo, hi;
    lo.x = f2b(a.x); lo.y = f2b(a.y); lo.z = f2b(a.z); lo.w = f2b(a.w);
    hi.x = f2b(b.x); hi.y = f2b(b.y); hi.z = f2b(b.z); hi.w = f2b(b.w);
    *(ushort4*)&xb[(size_t)i * 8] = lo;
    *(ushort4*)&xb[(size_t)i * 8 + 4] = hi;
}

__global__ __launch_bounds__(256) void k_transpose(const float* __restrict__ src,
    int src_ld, int col0, int R, unsigned short* __restrict__ dst)
{
    __shared__ float T[32][33];
    const int r0 = blockIdx.y * 32, c0 = blockIdx.x * 32;
    const int cx = threadIdx.x & 31, ry = threadIdx.x >> 5;
#pragma unroll
    for (int i = 0; i < 4; ++i)
        T[ry + 8 * i][cx] = src[(size_t)(r0 + ry + 8 * i) * src_ld + col0 + c0 + cx];
    __syncthreads();
#pragma unroll
    for (int i = 0; i < 4; ++i)
        dst[(size_t)(c0 + ry + 8 * i) * R + r0 + cx] = f2b(T[cx][ry + 8 * i]);
}

__global__ __launch_bounds__(256) void k_zero_kpad(unsigned short* __restrict__ kbuf)
{
    int t = blockIdx.x * 256 + threadIdx.x;
    int b = t >> 14, r = t & 16383;
    float4 z = {0.f, 0.f, 0.f, 0.f};
    *(float4*)&kbuf[(size_t)b * KPAD * DIM + (size_t)r * 8] = z;
}

// ---------------------------------------------------------------------------
// qk-proj (256^2 8-phase): q -> qbuf, k -> kbuf.
// ---------------------------------------------------------------------------
__global__ __launch_bounds__(512, 2) void k_gemm_qk(
    const unsigned short* __restrict__ xb, const unsigned short* __restrict__ wqkvT,
    unsigned short* __restrict__ qbuf, unsigned short* __restrict__ kbuf)
{
    __shared__ unsigned short lds[65536];
    const int tid = threadIdx.x, wid = tid >> 6, lane = tid & 63;
    const int wr = wid >> 2, wc = wid & 3;
    const int wg = blockIdx.x;
    const int x = (wg & 7) * 64 + (wg >> 3);
    const int bm = (x & 63) * 256;
    const int bn = (x >> 6) * 256;

    f32x4 acc[8][4];
    core256(xb + (size_t)bm * DIM, DIM, wqkvT + (size_t)bn * DIM, DIM, DIM,
            lds, acc, wid, lane, wr, wc);

    const int fr = lane & 15;
#pragma unroll
    for (int m = 0; m < 8; ++m) {
        const int row0 = bm + wr * 128 + m * 16 + (lane >> 4) * 4;
#pragma unroll
        for (int n = 0; n < 4; ++n) {
            const int col = bn + wc * 64 + n * 16 + fr;
            if (col < DIM) {
#pragma unroll
                for (int r = 0; r < 4; ++r)
                    qbuf[(size_t)(row0 + r) * DIM + col] = f2b(acc[m][n][r]);
            } else {
                const int d = col - DIM;
                const int b = row0 >> 12, tok0 = row0 & 4095;
#pragma unroll
                for (int r = 0; r < 4; ++r)
                    kbuf[((size_t)b * KPAD + 128 + tok0 + r) * DIM + d] = f2b(acc[m][n][r]);
            }
        }
    }
}

// ---------------------------------------------------------------------------
// out-proj (256^2 8-phase) + bias -> fp32 d_out.
// ---------------------------------------------------------------------------
__global__ __launch_bounds__(512, 2) void k_out(
    const unsigned short* __restrict__ aout, const unsigned short* __restrict__ woutT,
    const float* __restrict__ bias, float* __restrict__ out)
{
    __shared__ unsigned short lds[65536];
    const int tid = threadIdx.x, wid = tid >> 6, lane = tid & 63;
    const int wr = wid >> 2, wc = wid & 3;
    const int wg = blockIdx.x;
    const int x = (wg & 7) * 32 + (wg >> 3);
    const int bm = (x & 63) * 256;
    const int bn = (x >> 6) * 256;

    f32x4 acc[8][4];
    core256(aout + (size_t)bm * DIM, DIM, woutT + (size_t)bn * DIM, DIM, DIM,
            lds, acc, wid, lane, wr, wc);

    const int fr = lane & 15;
#pragma unroll
    for (int m = 0; m < 8; ++m) {
        const int row0 = bm + wr * 128 + m * 16 + (lane >> 4) * 4;
#pragma unroll
        for (int n = 0; n < 4; ++n) {
            const int col = bn + wc * 64 + n * 16 + fr;
            const float bb = bias[col];
#pragma unroll
            for (int r = 0; r < 4; ++r)
                out[(size_t)(row0 + r) * DIM + col] = acc[m][n][r] + bb;
        }
    }
}

// ===========================================================================
// Fused attention: QK^T + softmax + PV, one block per (mh, window).
// 512 thr = 8 waves. Phase 1: 64x256 scores (2M x 4N waves, acc[2][4]).
// Phase 2: PV over 8 d-tiles x 4 tok-slices (2M x 4N waves over 64x128,
// acc2[2][2]). All LDS tiles swizzled (read/write involutions):
//   As/Bs  [R][64]  : u7(P)  = P ^ (((P>>7)&7)<<4)   (src-preswz + swz read)
//   Ps     [64][256]: u9(P)  = P ^ (((P>>9)&7)<<4)
//   Bs2    [128][64]: u710(P)= P ^ ((((P>>7)^(P>>10))&7)<<4)
// LDS: As 8K + Bs 32K (Bs2 16K aliases As/Bs after phase 1) + Ps 32K +
// stats 2K = 74 KB -> 2 blocks/CU.
// ===========================================================================
__global__ __launch_bounds__(512) void k_attn(
    const unsigned short* __restrict__ qbuf, const unsigned short* __restrict__ kbuf,
    unsigned short* __restrict__ aout)
{
    __shared__ __align__(16) char smem[75776];
    unsigned short* As  = (unsigned short*)smem;            // 8 KB
    unsigned short* Bs  = (unsigned short*)(smem + 8192);   // 32 KB
    char*           Bs2 = smem;                             // 16 KB (alias)
    char*           Ps  = smem + 40960;                     // 32 KB
    float*          smax = (float*)(smem + 73728);          // 4*64
    float*          ssum = (float*)(smem + 74752);          // 4*64

    const int mh = blockIdx.x, win = blockIdx.y;
    const int b = win >> 5, w = win & 31;
    const int tid = threadIdx.x, wid = tid >> 6, lane = tid & 63;
    const int wr = wid >> 2, wc = wid & 3;
    const int hi = lane >> 4, fr = lane & 15;

    const unsigned short* Aq = qbuf + (size_t)(b * SEQ + w * WIN + mh * 64) * DIM;
    const unsigned short* Kp = kbuf + ((size_t)b * KPAD + w * WIN) * DIM;

    // ---------------- phase 1: scores = q . k2^T ----------------
    const int arow = wid * 8 + (lane >> 3);               // 0..63
    const int acs  = ((lane & 7) ^ (arow & 7)) * 8;       // pre-swizzled src col
    const int adst = arow * 64 + (lane & 7) * 8;          // linear LDS dest (elems)

    f32x4 acc[2][4];
#pragma unroll
    for (int m = 0; m < 2; ++m)
#pragma unroll
        for (int n = 0; n < 4; ++n) acc[m][n] = (f32x4){0.f, 0.f, 0.f, 0.f};

    for (int k0 = 0; k0 < DIM; k0 += 64) {
        gld_lds16(Aq + (size_t)arow * DIM + k0 + acs, As + adst);
#pragma unroll
        for (int it = 0; it < 4; ++it)
            gld_lds16(Kp + (size_t)(it * 64 + arow) * DIM + k0 + acs,
                      Bs + it * 4096 + adst);
        __syncthreads();
#pragma unroll
        for (int ks = 0; ks < 2; ++ks) {
            const int kb = ks * 64 + hi * 16;
            bf16x8 af[2], bf[4];
#pragma unroll
            for (int m = 0; m < 2; ++m) {
                const int P = (wr * 32 + m * 16 + fr) * 128 + kb;
                af[m] = *(const bf16x8*)((char*)As + (P ^ (((P >> 7) & 7) << 4)));
            }
#pragma unroll
            for (int n = 0; n < 4; ++n) {
                const int P = (wc * 64 + n * 16 + fr) * 128 + kb;
                bf[n] = *(const bf16x8*)((char*)Bs + (P ^ (((P >> 7) & 7) << 4)));
            }
#pragma unroll
            for (int m = 0; m < 2; ++m)
#pragma unroll
                for (int n = 0; n < 4; ++n)
                    acc[m][n] = __builtin_amdgcn_mfma_f32_16x16x32_bf16(
                        af[m], bf[n], acc[m][n], 0, 0, 0);
        }
        __syncthreads();
    }

    // ---------------- softmax (rows of 256) ----------------
    const float scale = 0.03125f;
    float ms[2][4][4];
#pragma unroll
    for (int m = 0; m < 2; ++m)
#pragma unroll
        for (int r = 0; r < 4; ++r) {
            const int qi = mh * 64 + wr * 32 + m * 16 + hi * 4 + r;
#pragma unroll
            for (int n = 0; n < 4; ++n) {
                const int jc = wc * 64 + n * 16 + fr;
                ms[m][n][r] = (jc > qi + WIN) ? -FLT_MAX : acc[m][n][r] * scale;
            }
        }

    float pmv[2][4];
#pragma unroll
    for (int m = 0; m < 2; ++m)
#pragma unroll
        for (int r = 0; r < 4; ++r) {
            float pm = fmaxf(fmaxf(ms[m][0][r], ms[m][1][r]),
                             fmaxf(ms[m][2][r], ms[m][3][r]));
#pragma unroll
            for (int off = 1; off < 16; off <<= 1) pm = fmaxf(pm, __shfl_xor(pm, off));
            pmv[m][r] = pm;
        }
    if (fr == 0) {
#pragma unroll
        for (int m = 0; m < 2; ++m)
#pragma unroll
            for (int r = 0; r < 4; ++r)
                smax[wc * 64 + wr * 32 + m * 16 + hi * 4 + r] = pmv[m][r];
    }
    __syncthreads();

    float e[2][4][4], psv[2][4];
#pragma unroll
    for (int m = 0; m < 2; ++m)
#pragma unroll
        for (int r = 0; r < 4; ++r) {
            const int rl = wr * 32 + m * 16 + hi * 4 + r;
            const float rm = fmaxf(fmaxf(smax[rl], smax[64 + rl]),
                                   fmaxf(smax[128 + rl], smax[192 + rl]));
            float s = 0.f;
#pragma unroll
            for (int n = 0; n < 4; ++n) {
                e[m][n][r] = expf(ms[m][n][r] - rm);
                s += e[m][n][r];
            }
#pragma unroll
            for (int off = 1; off < 16; off <<= 1) s += __shfl_xor(s, off);
            psv[m][r] = s;
        }
    if (fr == 0) {
#pragma unroll
        for (int m = 0; m < 2; ++m)
#pragma unroll
            for (int r = 0; r < 4; ++r)
                ssum[wc * 64 + wr * 32 + m * 16 + hi * 4 + r] = psv[m][r];
    }
    __syncthreads();

    // write P (bf16) into swizzled LDS Ps[64][256]
#pragma unroll
    for (int m = 0; m < 2; ++m)
#pragma unroll
        for (int r = 0; r < 4; ++r) {
            const int rl = wr * 32 + m * 16 + hi * 4 + r;
            const float inv =
                1.f / (ssum[rl] + ssum[64 + rl] + ssum[128 + rl] + ssum[192 + rl]);
#pragma unroll
            for (int n = 0; n < 4; ++n) {
                const int jc = wc * 64 + n * 16 + fr;
                const int P = rl * 512 + jc * 2;
                *(unsigned short*)(Ps + (P ^ (((P >> 9) & 7) << 4))) =
                    f2b(e[m][n][r] * inv);
            }
        }
    __syncthreads();   // Ps ready; Bs reads done -> Bs2 alias safe

    // ---------------- phase 2: out = P @ k2 ----------------
    const size_t orow0 = (size_t)(b * SEQ + w * WIN + mh * 64);
#pragma unroll 1
    for (int dt = 0; dt < 8; ++dt) {
        f32x4 acc2[2][2];
#pragma unroll
        for (int m = 0; m < 2; ++m)
#pragma unroll
            for (int n = 0; n < 2; ++n) acc2[m][n] = (f32x4){0.f, 0.f, 0.f, 0.f};

#pragma unroll 1
        for (int ts = 0; ts < 4; ++ts) {
            // stage Bs2[d 128][tok 64] transposed from kbuf (coalesced reads)
#pragma unroll
            for (int i = 0; i < 2; ++i) {
                const int tok = i * 32 + (tid >> 4);
                const int d0 = (tid & 15) * 8;
                u16x8 v = *(const u16x8*)&Kp[(size_t)(ts * 64 + tok) * DIM + dt * 128 + d0];
#pragma unroll
                for (int ee = 0; ee < 8; ++ee) {
                    const int P = (d0 + ee) * 128 + tok * 2;
                    *(unsigned short*)(Bs2 + (P ^ ((((P >> 7) ^ (P >> 10)) & 7) << 4))) = v[ee];
                }
            }
            __syncthreads();
#pragma unroll
            for (int ks = 0; ks < 2; ++ks) {
                bf16x8 pa[2], kb2[2];
                const int tb = ts * 128 + ks * 64 + hi * 16;
#pragma unroll
                for (int m = 0; m < 2; ++m) {
                    const int P = (wr * 32 + m * 16 + fr) * 512 + tb;
                    pa[m] = *(const bf16x8*)(Ps + (P ^ (((P >> 9) & 7) << 4)));
                }
#pragma unroll
                for (int n = 0; n < 2; ++n) {
                    const int P = (wc * 32 + n * 16 + fr) * 128 + ks * 64 + hi * 16;
                    kb2[n] = *(const bf16x8*)(Bs2 + (P ^ ((((P >> 7) ^ (P >> 10)) & 7) << 4)));
                }
#pragma unroll
                for (int m = 0; m < 2; ++m)
#pragma unroll
                    for (int n = 0; n < 2; ++n)
                        acc2[m][n] = __builtin_amdgcn_mfma_f32_16x16x32_bf16(
                            pa[m], kb2[n], acc2[m][n], 0, 0, 0);
            }
            __syncthreads();
        }
        // epilogue for this d-tile
#pragma unroll
        for (int m = 0; m < 2; ++m) {
            const int row0 = wr * 32 + m * 16 + hi * 4;
#pragma unroll
            for (int n = 0; n < 2; ++n) {
                const int col = dt * 128 + wc * 32 + n * 16 + fr;
#pragma unroll
                for (int r = 0; r < 4; ++r)
                    aout[(orow0 + row0 + r) * DIM + col] = f2b(acc2[m][n][r]);
            }
        }
    }
}

// ---------------------------------------------------------------------------
extern "C" void kernel_launch(void* const* d_in, const int* in_sizes, int n_in,
                              void* d_out, int out_size, void* d_ws, size_t ws_size,
                              hipStream_t stream)
{
    const float* x     = (const float*)d_in[0];
    const float* w_qkv = (const float*)d_in[1];
    const float* w_out = (const float*)d_in[2];
    const float* b_out = (const float*)d_in[3];
    float* out = (float*)d_out;

    char* p = (char*)d_ws;
    unsigned short* xb    = (unsigned short*)p; p += (size_t)NROWS * DIM * 2;
    unsigned short* wqkvT = (unsigned short*)p; p += (size_t)2 * DIM * DIM * 2;
    unsigned short* woutT = (unsigned short*)p; p += (size_t)DIM * DIM * 2;
    unsigned short* qbuf  = (unsigned short*)p; p += (size_t)NROWS * DIM * 2;
    unsigned short* kbuf  = (unsigned short*)p; p += (size_t)B_SZ * KPAD * DIM * 2;
    unsigned short* aout  = (unsigned short*)p; p += (size_t)NROWS * DIM * 2;

    k_prep_x<<<NROWS * DIM / 8 / 256, 256, 0, stream>>>(x, xb);
    k_transpose<<<dim3(2 * DIM / 32, DIM / 32), 256, 0, stream>>>(w_qkv, 3 * DIM, 0, DIM, wqkvT);
    k_transpose<<<dim3(DIM / 32, DIM / 32), 256, 0, stream>>>(w_out, DIM, 0, DIM, woutT);
    k_zero_kpad<<<256, 256, 0, stream>>>(kbuf);

    k_gemm_qk<<<512, 512, 0, stream>>>(xb, wqkvT, qbuf, kbuf);
    k_attn<<<dim3(2, B_SZ * NWIN), 512, 0, stream>>>(qbuf, kbuf, aout);
    k_out<<<256, 512, 0, stream>>>(aout, woutT, b_out, out);
}